// Round 15
// baseline (95.344 us; speedup 1.0000x reference)
//
#include <hip/hip_runtime.h>
#include <cstdint>

constexpr int BB = 4, SS = 4096, EE = 512, AA = 64;
constexpr int NT = 64;      // KV tiles (64-wide) per batch
constexpr int NSLOT = 272;  // compact chunk slots per batch (q-tile=128, CHUNK=4)

typedef __bf16 bf16x8 __attribute__((ext_vector_type(8)));
typedef float  f32x4  __attribute__((ext_vector_type(4)));
typedef float  f4     __attribute__((ext_vector_type(4)));
typedef unsigned short u16x4 __attribute__((ext_vector_type(4)));
typedef unsigned short u16x8 __attribute__((ext_vector_type(8)));

#define MFMA16(a, b, c) __builtin_amdgcn_mfma_f32_16x16x32_bf16((a), (b), (c), 0, 0, 0)

typedef const void __attribute__((address_space(1))) gvoid_t;
typedef void __attribute__((address_space(3))) lvoid_t;
__device__ __forceinline__ void gload16(const void* g, void* l) {
    __builtin_amdgcn_global_load_lds((gvoid_t*)g, (lvoid_t*)l, 16, 0, 0);
}

__device__ __forceinline__ unsigned short f2bf(float x) {
    union { float f; unsigned u; } v; v.f = x;
    unsigned r = v.u + 0x7fffu + ((v.u >> 16) & 1u);
    return (unsigned short)(r >> 16);
}
__device__ __forceinline__ float bf2f(unsigned short h) {
    union { unsigned u; float f; } v; v.u = ((unsigned)h) << 16;
    return v.f;
}
__device__ __forceinline__ unsigned short f2bfc(float x) {
    __bf16 h = (__bf16)x;
    return __builtin_bit_cast(unsigned short, h);
}
__device__ __forceinline__ bf16x8 as_bf16x8(u16x8 u) {
    union { u16x8 u; bf16x8 b; } v; v.u = u; return v.b;
}

// ---------------------------------------------------------------------------
// Kernel 0: split Wq/Wk/Wv (f32 [E,A]) into hi/lo bf16, TRANSPOSED [3][A][E]
// ---------------------------------------------------------------------------
__global__ void split_w_kernel(const float* __restrict__ Wq,
                               const float* __restrict__ Wk,
                               const float* __restrict__ Wv,
                               unsigned short* __restrict__ wt_h,
                               unsigned short* __restrict__ wt_l) {
    int idx = blockIdx.x * blockDim.x + threadIdx.x;
    if (idx >= 3 * EE * AA) return;
    int t = idx / (EE * AA);
    int rem = idx - t * (EE * AA);
    int k = rem >> 6;
    int n = rem & 63;
    const float* W = (t == 0) ? Wq : (t == 1) ? Wk : Wv;
    float x = W[k * AA + n];
    unsigned short h = f2bf(x);
    unsigned short l = f2bf(x - bf2f(h));
    int o = (t * AA + n) * EE + k;
    wt_h[o] = h;
    wt_l[o] = l;
}

// ---------------------------------------------------------------------------
// Kernel 1: projections via bf16x3-split MFMA. ROW-TILE 32, 128 threads,
// BK=128 -> 4 phases/block (was 8). LDS 48 KB: X[32][128] f32 16KB +
// Whi[64][128] 16KB + Wlo 16KB, all 16B-granule XOR-swizzled by row&7.
// Same global k/FMA order as BK=64 -> bit-identical results.
// q pre-scaled by 1/8 (exact).
// ---------------------------------------------------------------------------
__launch_bounds__(128)
__global__ void proj_kernel(const float* __restrict__ Xq,
                            const float* __restrict__ Xk,
                            const float* __restrict__ Xv,
                            const float* __restrict__ bq,
                            const float* __restrict__ bk,
                            const float* __restrict__ bv,
                            const unsigned short* __restrict__ wt_h,
                            const unsigned short* __restrict__ wt_l,
                            unsigned short* __restrict__ q_hi,
                            unsigned short* __restrict__ q_lo,
                            unsigned short* __restrict__ kv) {
    const int t = blockIdx.y;
    const float* X    = (t == 0) ? Xq : (t == 1) ? Xk : Xv;
    const float* bias = (t == 0) ? bq : (t == 1) ? bk : bv;
    const int row0 = blockIdx.x * 32;
    const int tid = threadIdx.x;
    const int lane = tid & 63, w = tid >> 6;   // w in {0,1}
    const int l15 = lane & 15, l4 = lane >> 4;

    __shared__ __align__(16) char smem[49152];
    // [0,16K): X f32 [32][128]: (r,g16) at r*512 + (g^(r&7))*16   (g=0..31)
    // [16K,32K): Whi [64][128] bf16: (n,g16) at n*256 + (g^(n&7))*16 (g=0..15)
    // [32K,48K): Wlo, same layout

    f32x4 acc[4];
#pragma unroll
    for (int j = 0; j < 4; ++j) acc[j] = (f32x4){0.f, 0.f, 0.f, 0.f};

    const unsigned short* wtH = wt_h + t * AA * EE;
    const unsigned short* wtL = wt_l + t * AA * EE;

    for (int kc0 = 0; kc0 < EE; kc0 += 128) {
        // ---- stage X tile (16 KB): 8 gload16/thread, inverse-swizzled src
#pragma unroll
        for (int s = 0; s < 8; ++s) {
            int e = s * 128 + tid;           // granule index 0..1023
            int r = e >> 5, g = e & 31;
            int cg = g ^ (r & 7);
            gload16(X + (size_t)(row0 + r) * EE + kc0 + cg * 4,
                    smem + e * 16);
        }
        // ---- stage W hi/lo (16+16 KB): 8+8 gload16/thread ----
#pragma unroll
        for (int s = 0; s < 8; ++s) {
            int e = s * 128 + tid;           // granule index 0..1023
            int n = e >> 4, g = e & 15;
            int cg = g ^ (n & 7);
            gload16(wtH + n * EE + kc0 + cg * 8, smem + 16384 + e * 16);
            gload16(wtL + n * EE + kc0 + cg * 8, smem + 32768 + e * 16);
        }
        asm volatile("s_waitcnt vmcnt(0)" ::: "memory");
        __syncthreads();

#pragma unroll
        for (int kc = 0; kc < 4; ++kc) {
            int r = w * 16 + l15;
            int g0 = (kc * 8 + l4 * 2) ^ (r & 7);
            int g1 = (kc * 8 + l4 * 2 + 1) ^ (r & 7);
            f4 va = *(const f4*)(smem + r * 512 + g0 * 16);
            f4 vb = *(const f4*)(smem + r * 512 + g1 * 16);
            u16x8 ahu, alu;
#pragma unroll
            for (int jj = 0; jj < 4; ++jj) {
                __bf16 h0 = (__bf16)va[jj];
                ahu[jj] = __builtin_bit_cast(unsigned short, h0);
                alu[jj] = f2bfc(va[jj] - (float)h0);
                __bf16 h1 = (__bf16)vb[jj];
                ahu[jj + 4] = __builtin_bit_cast(unsigned short, h1);
                alu[jj + 4] = f2bfc(vb[jj] - (float)h1);
            }
            bf16x8 a_h = as_bf16x8(ahu), a_l = as_bf16x8(alu);
#pragma unroll
            for (int j = 0; j < 4; ++j) {
                int n = j * 16 + l15;
                int byteB = n * 256 + (((kc * 4 + l4) ^ (n & 7)) << 4);
                bf16x8 b_h = as_bf16x8(*(const u16x8*)(smem + 16384 + byteB));
                bf16x8 b_l = as_bf16x8(*(const u16x8*)(smem + 32768 + byteB));
                acc[j] = MFMA16(a_h, b_h, acc[j]);
                acc[j] = MFMA16(a_h, b_l, acc[j]);
                acc[j] = MFMA16(a_l, b_h, acc[j]);
            }
        }
        __syncthreads();
    }

    // ---- epilogue: acc+bias -> LDS f32 [32][65] -> coalesced stores ----
    float* stage = (float*)smem;  // 8320 B
#pragma unroll
    for (int j = 0; j < 4; ++j) {
        int n = j * 16 + l15;
        float bv_ = bias[n];
#pragma unroll
        for (int reg = 0; reg < 4; ++reg) {
            int r = w * 16 + l4 * 4 + reg;
            stage[r * 65 + n] = acc[j][reg] + bv_;
        }
    }
    __syncthreads();

    if (t == 0) {
        int row = tid >> 2, n0 = (tid & 3) * 16;
        u16x8 h0, l0, h1, l1;
#pragma unroll
        for (int k = 0; k < 8; ++k) {
            float v = stage[row * 65 + n0 + k] * 0.125f;
            __bf16 hh = (__bf16)v;
            h0[k] = __builtin_bit_cast(unsigned short, hh);
            l0[k] = f2bfc(v - (float)hh);
        }
#pragma unroll
        for (int k = 0; k < 8; ++k) {
            float v = stage[row * 65 + n0 + 8 + k] * 0.125f;
            __bf16 hh = (__bf16)v;
            h1[k] = __builtin_bit_cast(unsigned short, hh);
            l1[k] = f2bfc(v - (float)hh);
        }
        size_t o = (size_t)(row0 + row) * AA + n0;
        *(u16x8*)(q_hi + o) = h0; *(u16x8*)(q_hi + o + 8) = h1;
        *(u16x8*)(q_lo + o) = l0; *(u16x8*)(q_lo + o + 8) = l1;
    } else {
        const int bb = row0 >> 12, kt = (row0 & 4095) >> 6;
        const int hb = (row0 >> 5) & 1;
        const size_t base = ((size_t)(bb * NT + kt) << 14) + (t == 2 ? 8192 : 0);
        const int ff = tid >> 5;
#pragma unroll
        for (int p = 0; p < 2; ++p) {
            int lane2 = (tid & 31) * 2 + p;
            u16x8 h, l;
            int f;
            if (t == 1) {
                f = (ff >> 1) * 4 + 2 * hb + (ff & 1);
                int n0 = (f >> 2) * 32 + (lane2 >> 4) * 8;
                int tt = (f & 3) * 16 + (lane2 & 15);
                int sr = tt & 31;
#pragma unroll
                for (int jj = 0; jj < 8; ++jj) {
                    float v = stage[sr * 65 + n0 + jj];
                    __bf16 hh = (__bf16)v;
                    h[jj] = __builtin_bit_cast(unsigned short, hh);
                    l[jj] = f2bfc(v - (float)hh);
                }
            } else {
                f = 4 * hb + ff;
                int n = (f & 3) * 16 + (lane2 & 15);
                int tt0 = (lane2 >> 4) * 8;
#pragma unroll
                for (int jj = 0; jj < 8; ++jj) {
                    float v = stage[(tt0 + jj) * 65 + n];
                    __bf16 hh = (__bf16)v;
                    h[jj] = __builtin_bit_cast(unsigned short, hh);
                    l[jj] = f2bfc(v - (float)hh);
                }
            }
            size_t o = base + (size_t)f * 512 + lane2 * 8;
            *(u16x8*)(kv + o) = h;
            *(u16x8*)(kv + o + 4096) = l;
        }
    }
}

// ---------------------------------------------------------------------------
// Kernel 2: per-tile V column sums -> exclusive suffix over tiles.
// ---------------------------------------------------------------------------
__launch_bounds__(64)
__global__ void sufv_kernel(const unsigned short* __restrict__ kv,
                            float* __restrict__ sufv) {
    const int b = blockIdx.x >> 6;
    const int a = blockIdx.x & 63;
    const int t = threadIdx.x;
    __shared__ float sums[64];
    const size_t tb = ((size_t)(b * NT + t) << 14) + 8192;
    const int j = a >> 4, l15i = a & 15;
    float s = 0.f;
#pragma unroll
    for (int c2 = 0; c2 < 2; ++c2) {
#pragma unroll
        for (int l4i = 0; l4i < 4; ++l4i) {
            size_t off = tb + (((c2 * 4 + j) * 64 + l4i * 16 + l15i) << 3);
            u16x8 h = *(const u16x8*)(kv + off);
            u16x8 l = *(const u16x8*)(kv + off + 4096);
#pragma unroll
            for (int q = 0; q < 8; ++q) s += bf2f(h[q]) + bf2f(l[q]);
        }
    }
    sums[t] = s;
    __syncthreads();
    float suf = 0.f;
    for (int jj = t + 1; jj < 64; ++jj) suf += sums[jj];
    sufv[((size_t)(b * 64 + a)) * 64 + t] = suf;
}

// ---------------------------------------------------------------------------
// Kernel 3: attention chunk. q-tile=128, 8 waves, CHUNK=4. TWO KV TILES PER
// PHASE: stage 64KB (tiles kt,kt+1 contiguous in kv) -> vmcnt(0)+barrier ->
// compute both tiles back-to-back -> barrier. Phases per block halve.
// LDS 80 KB -> 2 blocks/CU (16 waves). Bit-identical FMA order.
// ---------------------------------------------------------------------------
#define ATTN_TILE(LB, KT)                                                      \
  do {                                                                         \
    const char* lb = (LB);                                                     \
    f32x4 sc[4];                                                               \
    _Pragma("unroll") for (int j = 0; j < 4; ++j)                              \
        sc[j] = (f32x4){0.f, 0.f, 0.f, 0.f};                                   \
    __builtin_amdgcn_s_setprio(1);                                             \
    _Pragma("unroll") for (int kc = 0; kc < 2; ++kc) {                         \
      _Pragma("unroll") for (int j2 = 0; j2 < 4; ++j2) {                       \
        int f = kc * 4 + j2;                                                   \
        bf16x8 h = as_bf16x8(*(const u16x8*)(lb + f * 1024 + lane * 16));      \
        bf16x8 l = as_bf16x8(*(const u16x8*)(lb + 8192 + f * 1024 + lane * 16));\
        sc[j2] = MFMA16(h, qh[kc], sc[j2]);                                    \
        sc[j2] = MFMA16(l, qh[kc], sc[j2]);                                    \
        sc[j2] = MFMA16(h, ql[kc], sc[j2]);                                    \
      }                                                                        \
    }                                                                          \
    __builtin_amdgcn_s_setprio(0);                                             \
    const int dq = qbase - 64 * (KT);                                          \
    const bool anyMask = (dq < 63);                                            \
    _Pragma("unroll") for (int j2 = 0; j2 < 4; ++j2) {                         \
      u16x4 p4;                                                                \
      _Pragma("unroll") for (int reg = 0; reg < 4; ++reg) {                    \
        float sv_ = sc[j2][reg];                                               \
        if (anyMask) {                                                         \
          int tl = j2 * 16 + l4 * 4 + reg;                                     \
          if (tl > dq + l15) sv_ = 0.f;                                        \
        }                                                                      \
        float p = __expf(sv_);                                                 \
        lsum += p;                                                             \
        p4[reg] = f2bf(p);                                                     \
      }                                                                        \
      int byte = (l15 * 128 + j2 * 32 + l4 * 8) ^ ((l15 & 7) << 4);            \
      *(u16x4*)((char*)plds[w] + byte) = p4;                                   \
    }                                                                          \
    __builtin_amdgcn_s_setprio(1);                                             \
    _Pragma("unroll") for (int c2 = 0; c2 < 2; ++c2) {                         \
      int byteA = (l15 * 128 + c2 * 64 + l4 * 16) ^ ((l15 & 7) << 4);          \
      bf16x8 pf = as_bf16x8(*(const u16x8*)((const char*)plds[w] + byteA));    \
      _Pragma("unroll") for (int j = 0; j < 4; ++j) {                          \
        int f = c2 * 4 + j;                                                    \
        bf16x8 vh = as_bf16x8(*(const u16x8*)(lb + 16384 + f * 1024 + lane * 16));\
        bf16x8 vl = as_bf16x8(*(const u16x8*)(lb + 24576 + f * 1024 + lane * 16));\
        facc[j] = MFMA16(pf, vh, facc[j]);                                     \
        facc[j] = MFMA16(pf, vl, facc[j]);                                     \
      }                                                                        \
    }                                                                          \
    __builtin_amdgcn_s_setprio(0);                                             \
  } while (0)

__launch_bounds__(512)
__global__ void attn_chunk_kernel(const unsigned short* __restrict__ q_hi,
                                  const unsigned short* __restrict__ q_lo,
                                  const unsigned short* __restrict__ kv,
                                  float* __restrict__ facc_part,
                                  float* __restrict__ l_part) {
    const int idx = (int)blockIdx.x;          // 0..4*NSLOT-1
    const int b = idx & 3;
    const int s = (NSLOT - 1) - (idx >> 2);   // heavy-first logical slot
    int k = (int)sqrtf((float)s + 0.5f);
    while (k * k > s) --k;
    while ((k + 1) * (k + 1) <= s) ++k;
    int i, c;
    if (s < k * (k + 1)) { i = 2 * k - 1; c = s - k * k; }
    else                 { i = 2 * k;     c = s - k * (k + 1); }
    const int t_begin = c * 4;
    const int tmax = 2 * i + 2;
    const int t_end = (t_begin + 4 < tmax) ? t_begin + 4 : tmax;

    const int tid = threadIdx.x;
    const int lane = tid & 63, w = tid >> 6;  // w in [0,8)
    const int l15 = lane & 15, l4 = lane >> 4;

    __shared__ __align__(16) unsigned short kvbuf[2][16384];  // 64 KB (2 tiles)
    __shared__ __align__(16) unsigned short plds[8][1024];    // 16 KB

    bf16x8 qh[2], ql[2];
    {
        size_t qrow = (size_t)(b * SS + i * 128 + w * 16 + l15) * AA;
#pragma unroll
        for (int kc = 0; kc < 2; ++kc) {
            qh[kc] = as_bf16x8(*(const u16x8*)(q_hi + qrow + kc * 32 + l4 * 8));
            ql[kc] = as_bf16x8(*(const u16x8*)(q_lo + qrow + kc * 32 + l4 * 8));
        }
    }

    f32x4 facc[4];
#pragma unroll
    for (int j = 0; j < 4; ++j) facc[j] = (f32x4){0.f, 0.f, 0.f, 0.f};
    float lsum = 0.f;

    const int qbase = i * 128 + w * 16;
    const char* gbase = (const char*)kv + (((size_t)(b * NT)) << 15) + tid * 16;

    for (int kt = t_begin; kt < t_end; kt += 2) {
        const int np = (kt + 1 < t_end) ? 2 : 1;
        // ---- stage np tiles (np*32KB contiguous) ----
        {
            const char* gt = gbase + (((size_t)kt) << 15);
            char* lw = (char*)kvbuf[0] + tid * 16;
#pragma unroll
            for (int p = 0; p < 4; ++p) gload16(gt + p * 8192, lw + p * 8192);
            if (np == 2) {
#pragma unroll
                for (int p = 4; p < 8; ++p) gload16(gt + p * 8192, lw + p * 8192);
            }
        }
        asm volatile("s_waitcnt vmcnt(0)" ::: "memory");
        __syncthreads();

        ATTN_TILE((const char*)kvbuf[0], kt);
        if (np == 2) ATTN_TILE((const char*)kvbuf[1], kt + 1);

        if (kt + 2 < t_end) __syncthreads();
    }

    {
        float rs = lsum;
        rs += __shfl_xor(rs, 16);
        rs += __shfl_xor(rs, 32);
        const size_t slot = (size_t)b * NSLOT + s;
        if (l4 == 0)
            l_part[slot * 128 + w * 16 + l15] = rs;

        float* fp = facc_part + slot * 8192;
#pragma unroll
        for (int j = 0; j < 4; ++j) {
#pragma unroll
            for (int reg = 0; reg < 4; ++reg) {
                int row = w * 16 + l4 * 4 + reg, a = j * 16 + l15;
                fp[row * 64 + a] = facc[j][reg];
            }
        }
    }
}

// ---------------------------------------------------------------------------
// Kernel 4: combine partials + closed-form masked region (R12 verbatim).
// ---------------------------------------------------------------------------
__launch_bounds__(256)
__global__ void combine_kernel(const float* __restrict__ facc_part,
                               const float* __restrict__ l_part,
                               const float* __restrict__ sufv,
                               float* __restrict__ out) {
    const int i64 = blockIdx.x;
    const int b = blockIdx.y;
    const int tid = threadIdx.x;
    const int i128 = i64 >> 1;
    const int nch = (i128 >> 1) + 1;
    const int k2 = i128 >> 1;
    const int C = (i128 & 1) ? (k2 + 1) * (k2 + 1) : k2 * (k2 + 1);
    const size_t slot0 = (size_t)b * NSLOT + C;
    const int rbase = (i64 & 1) * 64;
    __shared__ float linv[64];
    __shared__ float sv[64];
    if (tid < 64) {
        float l = 64.0f * (float)(NT - 2 * i128 - 2);
        for (int cc = 0; cc < nch; ++cc)
            l += l_part[(slot0 + cc) * 128 + rbase + tid];
        linv[tid] = 1.f / l;
        sv[tid] = sufv[((size_t)(b * 64 + tid)) * 64 + (2 * i128 + 1)];
    }
    __syncthreads();
    float* ob = out + ((size_t)(b * SS + i64 * 64)) * AA;
#pragma unroll
    for (int k = 0; k < 4; ++k) {
        int e = (tid + k * 256) * 4;
        int row = e >> 6, a = e & 63;
        f4 acc = {sv[a], sv[a + 1], sv[a + 2], sv[a + 3]};
        for (int cc = 0; cc < nch; ++cc) {
            f4 v = *(const f4*)(facc_part + (slot0 + cc) * 8192 + (rbase + row) * 64 + a);
            acc += v;
        }
        acc *= linv[row];
        *(f4*)(ob + e) = acc;
    }
}

// ---------------------------------------------------------------------------
extern "C" void kernel_launch(void* const* d_in, const int* in_sizes, int n_in,
                              void* d_out, int out_size, void* d_ws, size_t ws_size,
                              hipStream_t stream) {
    const float* query = (const float*)d_in[0];
    const float* key   = (const float*)d_in[1];
    const float* value = (const float*)d_in[2];
    const float* Wq    = (const float*)d_in[3];
    const float* bq    = (const float*)d_in[4];
    const float* Wk    = (const float*)d_in[5];
    const float* bk    = (const float*)d_in[6];
    const float* Wv    = (const float*)d_in[7];
    const float* bv    = (const float*)d_in[8];

    char* ws = (char*)d_ws;
    const size_t MB = 1u << 20;
    unsigned short* q_hi = (unsigned short*)(ws + 0 * MB);    // 2 MB
    unsigned short* q_lo = (unsigned short*)(ws + 2 * MB);    // 2 MB
    unsigned short* kv   = (unsigned short*)(ws + 4 * MB);    // 8 MB
    float* sufv      = (float*)(ws + 12 * MB);                // 64 KB
    float* l_part    = (float*)(ws + 13 * MB);                // 557 KB
    float* facc_part = (float*)(ws + 14 * MB);                // 35.7 MB
    unsigned short* wt_h = (unsigned short*)(ws + 52 * MB);   // 192 KB
    unsigned short* wt_l = wt_h + 3 * AA * EE;                // 192 KB

    split_w_kernel<<<(3 * EE * AA + 255) / 256, 256, 0, stream>>>(Wq, Wk, Wv, wt_h, wt_l);
    proj_kernel<<<dim3(BB * SS / 32, 3), 128, 0, stream>>>(
        query, key, value, bq, bk, bv, wt_h, wt_l, q_hi, q_lo, kv);
    sufv_kernel<<<BB * AA, 64, 0, stream>>>(kv, sufv);
    attn_chunk_kernel<<<dim3(4 * NSLOT, 1), 512, 0, stream>>>(
        q_hi, q_lo, kv, facc_part, l_part);
    combine_kernel<<<dim3(NT, BB), 256, 0, stream>>>(facc_part, l_part, sufv, (float*)d_out);
}

// Round 16
// 90.460 us; speedup vs baseline: 1.0540x; 1.0540x over previous
//
#include <hip/hip_runtime.h>
#include <cstdint>

constexpr int BB = 4, SS = 4096, EE = 512, AA = 64;
constexpr int NT = 64;      // KV tiles (64-wide) per batch
constexpr int NSLOT = 272;  // compact chunk slots per batch (q-tile=128, CHUNK=4)
constexpr int TSH = 12288;  // kv tile stride in shorts: [kh 4096|vh 4096|vl 4096]

typedef __bf16 bf16x8 __attribute__((ext_vector_type(8)));
typedef float  f32x4  __attribute__((ext_vector_type(4)));
typedef float  f4     __attribute__((ext_vector_type(4)));
typedef unsigned short u16x4 __attribute__((ext_vector_type(4)));
typedef unsigned short u16x8 __attribute__((ext_vector_type(8)));

#define MFMA16(a, b, c) __builtin_amdgcn_mfma_f32_16x16x32_bf16((a), (b), (c), 0, 0, 0)

typedef const void __attribute__((address_space(1))) gvoid_t;
typedef void __attribute__((address_space(3))) lvoid_t;
__device__ __forceinline__ void gload16(const void* g, void* l) {
    __builtin_amdgcn_global_load_lds((gvoid_t*)g, (lvoid_t*)l, 16, 0, 0);
}

__device__ __forceinline__ unsigned short f2bf(float x) {
    union { float f; unsigned u; } v; v.f = x;
    unsigned r = v.u + 0x7fffu + ((v.u >> 16) & 1u);
    return (unsigned short)(r >> 16);
}
__device__ __forceinline__ float bf2f(unsigned short h) {
    union { unsigned u; float f; } v; v.u = ((unsigned)h) << 16;
    return v.f;
}
__device__ __forceinline__ unsigned short f2bfc(float x) {
    __bf16 h = (__bf16)x;
    return __builtin_bit_cast(unsigned short, h);
}
__device__ __forceinline__ bf16x8 as_bf16x8(u16x8 u) {
    union { u16x8 u; bf16x8 b; } v; v.u = u; return v.b;
}

// ---------------------------------------------------------------------------
// Kernel 0: split Wq/Wk/Wv (f32 [E,A]) into hi/lo bf16, TRANSPOSED [3][A][E]
// ---------------------------------------------------------------------------
__global__ void split_w_kernel(const float* __restrict__ Wq,
                               const float* __restrict__ Wk,
                               const float* __restrict__ Wv,
                               unsigned short* __restrict__ wt_h,
                               unsigned short* __restrict__ wt_l) {
    int idx = blockIdx.x * blockDim.x + threadIdx.x;
    if (idx >= 3 * EE * AA) return;
    int t = idx / (EE * AA);
    int rem = idx - t * (EE * AA);
    int k = rem >> 6;
    int n = rem & 63;
    const float* W = (t == 0) ? Wq : (t == 1) ? Wk : Wv;
    float x = W[k * AA + n];
    unsigned short h = f2bf(x);
    unsigned short l = f2bf(x - bf2f(h));
    int o = (t * AA + n) * EE + k;
    wt_h[o] = h;
    wt_l[o] = l;
}

// ---------------------------------------------------------------------------
// Kernel 1: projections via bf16x3-split MFMA (R13 structure: ROW-TILE 32,
// 128 threads, BK=64, 24KB LDS). q pre-scaled by 1/8 (exact).
// kv layout: tile stride 12288 shorts = [kh 4096 | vh 4096 | vl 4096].
// K lo is NOT written (dropped from attn's QK — see R16 theory).
// ---------------------------------------------------------------------------
__launch_bounds__(128)
__global__ void proj_kernel(const float* __restrict__ Xq,
                            const float* __restrict__ Xk,
                            const float* __restrict__ Xv,
                            const float* __restrict__ bq,
                            const float* __restrict__ bk,
                            const float* __restrict__ bv,
                            const unsigned short* __restrict__ wt_h,
                            const unsigned short* __restrict__ wt_l,
                            unsigned short* __restrict__ q_hi,
                            unsigned short* __restrict__ q_lo,
                            unsigned short* __restrict__ kv) {
    const int t = blockIdx.y;
    const float* X    = (t == 0) ? Xq : (t == 1) ? Xk : Xv;
    const float* bias = (t == 0) ? bq : (t == 1) ? bk : bv;
    const int row0 = blockIdx.x * 32;
    const int tid = threadIdx.x;
    const int lane = tid & 63, w = tid >> 6;   // w in {0,1}
    const int l15 = lane & 15, l4 = lane >> 4;

    __shared__ __align__(16) char smem[24576];

    f32x4 acc[4];
#pragma unroll
    for (int j = 0; j < 4; ++j) acc[j] = (f32x4){0.f, 0.f, 0.f, 0.f};

    const unsigned short* wtH = wt_h + t * AA * EE;
    const unsigned short* wtL = wt_l + t * AA * EE;

    for (int kc0 = 0; kc0 < EE; kc0 += 64) {
#pragma unroll
        for (int s = 0; s < 4; ++s) {
            int r = s * 8 + (tid >> 4);
            int c4 = (tid & 15) ^ (r & 7);
            gload16(X + (size_t)(row0 + r) * EE + kc0 + c4 * 4,
                    smem + s * 2048 + tid * 16);
        }
#pragma unroll
        for (int s = 0; s < 4; ++s) {
            int n = s * 16 + (tid >> 3);
            int cg = (tid & 7) ^ (n & 7);
            gload16(wtH + n * EE + kc0 + cg * 8,
                    smem + 8192 + s * 2048 + tid * 16);
            gload16(wtL + n * EE + kc0 + cg * 8,
                    smem + 16384 + s * 2048 + tid * 16);
        }
        asm volatile("s_waitcnt vmcnt(0)" ::: "memory");
        __syncthreads();

#pragma unroll
        for (int kc = 0; kc < 2; ++kc) {
            int r = w * 16 + l15;
            int c4a = (kc * 8 + l4 * 2) ^ (r & 7);
            int c4b = (kc * 8 + l4 * 2 + 1) ^ (r & 7);
            f4 va = *(const f4*)(smem + r * 256 + c4a * 16);
            f4 vb = *(const f4*)(smem + r * 256 + c4b * 16);
            u16x8 ahu, alu;
#pragma unroll
            for (int jj = 0; jj < 4; ++jj) {
                __bf16 h0 = (__bf16)va[jj];
                ahu[jj] = __builtin_bit_cast(unsigned short, h0);
                alu[jj] = f2bfc(va[jj] - (float)h0);
                __bf16 h1 = (__bf16)vb[jj];
                ahu[jj + 4] = __builtin_bit_cast(unsigned short, h1);
                alu[jj + 4] = f2bfc(vb[jj] - (float)h1);
            }
            bf16x8 a_h = as_bf16x8(ahu), a_l = as_bf16x8(alu);
#pragma unroll
            for (int j = 0; j < 4; ++j) {
                int n = j * 16 + l15;
                int byteB = n * 128 + (((kc * 4 + l4) ^ (n & 7)) << 4);
                bf16x8 b_h = as_bf16x8(*(const u16x8*)(smem + 8192 + byteB));
                bf16x8 b_l = as_bf16x8(*(const u16x8*)(smem + 16384 + byteB));
                acc[j] = MFMA16(a_h, b_h, acc[j]);
                acc[j] = MFMA16(a_h, b_l, acc[j]);
                acc[j] = MFMA16(a_l, b_h, acc[j]);
            }
        }
        __syncthreads();
    }

    float* stage = (float*)smem;  // 32*65*4 = 8320 B
#pragma unroll
    for (int j = 0; j < 4; ++j) {
        int n = j * 16 + l15;
        float bv_ = bias[n];
#pragma unroll
        for (int reg = 0; reg < 4; ++reg) {
            int r = w * 16 + l4 * 4 + reg;
            stage[r * 65 + n] = acc[j][reg] + bv_;
        }
    }
    __syncthreads();

    if (t == 0) {
        int row = tid >> 2, n0 = (tid & 3) * 16;
        u16x8 h0, l0, h1, l1;
#pragma unroll
        for (int k = 0; k < 8; ++k) {
            float v = stage[row * 65 + n0 + k] * 0.125f;   // pre-scale (exact)
            __bf16 hh = (__bf16)v;
            h0[k] = __builtin_bit_cast(unsigned short, hh);
            l0[k] = f2bfc(v - (float)hh);
        }
#pragma unroll
        for (int k = 0; k < 8; ++k) {
            float v = stage[row * 65 + n0 + 8 + k] * 0.125f;
            __bf16 hh = (__bf16)v;
            h1[k] = __builtin_bit_cast(unsigned short, hh);
            l1[k] = f2bfc(v - (float)hh);
        }
        size_t o = (size_t)(row0 + row) * AA + n0;
        *(u16x8*)(q_hi + o) = h0; *(u16x8*)(q_hi + o + 8) = h1;
        *(u16x8*)(q_lo + o) = l0; *(u16x8*)(q_lo + o + 8) = l1;
    } else if (t == 1) {
        // K: write hi only, tile base (bb*NT+kt)*TSH
        const int bb = row0 >> 12, kt = (row0 & 4095) >> 6;
        const int hb = (row0 >> 5) & 1;
        const size_t base = (size_t)(bb * NT + kt) * TSH;
        const int ff = tid >> 5;
#pragma unroll
        for (int p = 0; p < 2; ++p) {
            int lane2 = (tid & 31) * 2 + p;
            int f = (ff >> 1) * 4 + 2 * hb + (ff & 1);
            int n0 = (f >> 2) * 32 + (lane2 >> 4) * 8;
            int tt = (f & 3) * 16 + (lane2 & 15);
            int sr = tt & 31;
            u16x8 h;
#pragma unroll
            for (int jj = 0; jj < 8; ++jj)
                h[jj] = f2bfc(stage[sr * 65 + n0 + jj]);
            *(u16x8*)(kv + base + (size_t)f * 512 + lane2 * 8) = h;
        }
    } else {
        // V: hi at +4096, lo at +8192 within tile
        const int bb = row0 >> 12, kt = (row0 & 4095) >> 6;
        const int hb = (row0 >> 5) & 1;
        const size_t base = (size_t)(bb * NT + kt) * TSH + 4096;
        const int ff = tid >> 5;
#pragma unroll
        for (int p = 0; p < 2; ++p) {
            int lane2 = (tid & 31) * 2 + p;
            int f = 4 * hb + ff;
            int n = (f & 3) * 16 + (lane2 & 15);
            int tt0 = (lane2 >> 4) * 8;
            u16x8 h, l;
#pragma unroll
            for (int jj = 0; jj < 8; ++jj) {
                float v = stage[(tt0 + jj) * 65 + n];
                __bf16 hh = (__bf16)v;
                h[jj] = __builtin_bit_cast(unsigned short, hh);
                l[jj] = f2bfc(v - (float)hh);
            }
            size_t o = base + (size_t)f * 512 + lane2 * 8;
            *(u16x8*)(kv + o) = h;
            *(u16x8*)(kv + o + 4096) = l;
        }
    }
}

// ---------------------------------------------------------------------------
// Kernel 2: per-tile V column sums -> exclusive suffix over tiles.
// ---------------------------------------------------------------------------
__launch_bounds__(64)
__global__ void sufv_kernel(const unsigned short* __restrict__ kv,
                            float* __restrict__ sufv) {
    const int b = blockIdx.x >> 6;
    const int a = blockIdx.x & 63;
    const int t = threadIdx.x;
    __shared__ float sums[64];
    const size_t tb = (size_t)(b * NT + t) * TSH + 4096;   // vh base
    const int j = a >> 4, l15i = a & 15;
    float s = 0.f;
#pragma unroll
    for (int c2 = 0; c2 < 2; ++c2) {
#pragma unroll
        for (int l4i = 0; l4i < 4; ++l4i) {
            size_t off = tb + (((c2 * 4 + j) * 64 + l4i * 16 + l15i) << 3);
            u16x8 h = *(const u16x8*)(kv + off);
            u16x8 l = *(const u16x8*)(kv + off + 4096);
#pragma unroll
            for (int q = 0; q < 8; ++q) s += bf2f(h[q]) + bf2f(l[q]);
        }
    }
    sums[t] = s;
    __syncthreads();
    float suf = 0.f;
    for (int jj = t + 1; jj < 64; ++jj) suf += sums[jj];
    sufv[((size_t)(b * 64 + a)) * 64 + t] = suf;
}

// ---------------------------------------------------------------------------
// Kernel 3: attention chunk. q-tile=128, 8 waves, CHUNK=4, single 24KB kvbuf
// [kh|vh|vl] -> LDS 40KB -> 4 blocks/CU. QK = Kh*Qh + Kh*Ql (K hi-only;
// 16 MFMA was 24); PV = P*(Vh+Vl). Stage 24KB/tile (was 32).
// ---------------------------------------------------------------------------
__launch_bounds__(512)
__global__ void attn_chunk_kernel(const unsigned short* __restrict__ q_hi,
                                  const unsigned short* __restrict__ q_lo,
                                  const unsigned short* __restrict__ kv,
                                  float* __restrict__ facc_part,
                                  float* __restrict__ l_part) {
    const int idx = (int)blockIdx.x;          // 0..4*NSLOT-1
    const int b = idx & 3;
    const int s = (NSLOT - 1) - (idx >> 2);   // heavy-first logical slot
    int k = (int)sqrtf((float)s + 0.5f);
    while (k * k > s) --k;
    while ((k + 1) * (k + 1) <= s) ++k;
    int i, c;
    if (s < k * (k + 1)) { i = 2 * k - 1; c = s - k * k; }
    else                 { i = 2 * k;     c = s - k * (k + 1); }
    const int t_begin = c * 4;
    const int tmax = 2 * i + 2;
    const int t_end = (t_begin + 4 < tmax) ? t_begin + 4 : tmax;

    const int tid = threadIdx.x;
    const int lane = tid & 63, w = tid >> 6;  // w in [0,8)
    const int l15 = lane & 15, l4 = lane >> 4;

    __shared__ __align__(16) unsigned short kvbuf[TSH];     // 24 KB
    __shared__ __align__(16) unsigned short plds[8][1024];  // 16 KB

    bf16x8 qh[2], ql[2];
    {
        size_t qrow = (size_t)(b * SS + i * 128 + w * 16 + l15) * AA;
#pragma unroll
        for (int kc = 0; kc < 2; ++kc) {
            qh[kc] = as_bf16x8(*(const u16x8*)(q_hi + qrow + kc * 32 + l4 * 8));
            ql[kc] = as_bf16x8(*(const u16x8*)(q_lo + qrow + kc * 32 + l4 * 8));
        }
    }

    f32x4 facc[4];
#pragma unroll
    for (int j = 0; j < 4; ++j) facc[j] = (f32x4){0.f, 0.f, 0.f, 0.f};
    float lsum = 0.f;

    const char* lb = (const char*)kvbuf;
    const int qbase = i * 128 + w * 16;
    const char* gbase = (const char*)kv + (size_t)(b * NT) * (TSH * 2) + tid * 16;

    for (int kt = t_begin; kt < t_end; ++kt) {
        // ---- stage 24KB tile: 512 thr x 3 x 16B linear ----
        {
            const char* gt = gbase + (size_t)kt * (TSH * 2);
            char* lw = (char*)kvbuf + tid * 16;
#pragma unroll
            for (int p = 0; p < 3; ++p) gload16(gt + p * 8192, lw + p * 8192);
        }
        asm volatile("s_waitcnt vmcnt(0)" ::: "memory");
        __syncthreads();

        // ---- QK^T swapped (A=Kh, B=Qh then Ql): D[t][q], q = lane&15 ----
        f32x4 sc[4];
#pragma unroll
        for (int j = 0; j < 4; ++j) sc[j] = (f32x4){0.f, 0.f, 0.f, 0.f};
        __builtin_amdgcn_s_setprio(1);
#pragma unroll
        for (int kc = 0; kc < 2; ++kc) {
#pragma unroll
            for (int j2 = 0; j2 < 4; ++j2) {
                int f = kc * 4 + j2;
                bf16x8 h = as_bf16x8(*(const u16x8*)(lb + f * 1024 + lane * 16));
                sc[j2] = MFMA16(h, qh[kc], sc[j2]);
                sc[j2] = MFMA16(h, ql[kc], sc[j2]);
            }
        }
        __builtin_amdgcn_s_setprio(0);

        // ---- mult-mask (boundary tiles), exp, packed P-write, lsum ----
        const int dq = qbase - 64 * kt;
        const bool anyMask = (dq < 63);
#pragma unroll
        for (int j2 = 0; j2 < 4; ++j2) {
            u16x4 p4;
#pragma unroll
            for (int reg = 0; reg < 4; ++reg) {
                float sv_ = sc[j2][reg];
                if (anyMask) {
                    int tl = j2 * 16 + l4 * 4 + reg;
                    if (tl > dq + l15) sv_ = 0.f;
                }
                float p = __expf(sv_);
                lsum += p;
                p4[reg] = f2bf(p);
            }
            int byte = (l15 * 128 + j2 * 32 + l4 * 8) ^ ((l15 & 7) << 4);
            *(u16x4*)((char*)plds[w] + byte) = p4;
        }

        // ---- PV: facc += P @ (Vhi + Vlo); vh at +8192B, vl at +16384B ----
        __builtin_amdgcn_s_setprio(1);
#pragma unroll
        for (int c2 = 0; c2 < 2; ++c2) {
            int byteA = (l15 * 128 + c2 * 64 + l4 * 16) ^ ((l15 & 7) << 4);
            bf16x8 pf = as_bf16x8(*(const u16x8*)((const char*)plds[w] + byteA));
#pragma unroll
            for (int j = 0; j < 4; ++j) {
                int f = c2 * 4 + j;
                bf16x8 vh = as_bf16x8(*(const u16x8*)(lb + 8192 + f * 1024 + lane * 16));
                bf16x8 vl = as_bf16x8(*(const u16x8*)(lb + 16384 + f * 1024 + lane * 16));
                facc[j] = MFMA16(pf, vh, facc[j]);
                facc[j] = MFMA16(pf, vl, facc[j]);
            }
        }
        __builtin_amdgcn_s_setprio(0);

        // ---- protect kvbuf before next tile's stage overwrites ----
        if (kt + 1 < t_end) __syncthreads();
    }

    {
        float rs = lsum;
        rs += __shfl_xor(rs, 16);
        rs += __shfl_xor(rs, 32);
        const size_t slot = (size_t)b * NSLOT + s;
        if (l4 == 0)
            l_part[slot * 128 + w * 16 + l15] = rs;

        float* fp = facc_part + slot * 8192;
#pragma unroll
        for (int j = 0; j < 4; ++j) {
#pragma unroll
            for (int reg = 0; reg < 4; ++reg) {
                int row = w * 16 + l4 * 4 + reg, a = j * 16 + l15;
                fp[row * 64 + a] = facc[j][reg];
            }
        }
    }
}

// ---------------------------------------------------------------------------
// Kernel 4: combine partials + closed-form masked region (R12 verbatim).
// ---------------------------------------------------------------------------
__launch_bounds__(256)
__global__ void combine_kernel(const float* __restrict__ facc_part,
                               const float* __restrict__ l_part,
                               const float* __restrict__ sufv,
                               float* __restrict__ out) {
    const int i64 = blockIdx.x;
    const int b = blockIdx.y;
    const int tid = threadIdx.x;
    const int i128 = i64 >> 1;
    const int nch = (i128 >> 1) + 1;
    const int k2 = i128 >> 1;
    const int C = (i128 & 1) ? (k2 + 1) * (k2 + 1) : k2 * (k2 + 1);
    const size_t slot0 = (size_t)b * NSLOT + C;
    const int rbase = (i64 & 1) * 64;
    __shared__ float linv[64];
    __shared__ float sv[64];
    if (tid < 64) {
        float l = 64.0f * (float)(NT - 2 * i128 - 2);
        for (int cc = 0; cc < nch; ++cc)
            l += l_part[(slot0 + cc) * 128 + rbase + tid];
        linv[tid] = 1.f / l;
        sv[tid] = sufv[((size_t)(b * 64 + tid)) * 64 + (2 * i128 + 1)];
    }
    __syncthreads();
    float* ob = out + ((size_t)(b * SS + i64 * 64)) * AA;
#pragma unroll
    for (int k = 0; k < 4; ++k) {
        int e = (tid + k * 256) * 4;
        int row = e >> 6, a = e & 63;
        f4 acc = {sv[a], sv[a + 1], sv[a + 2], sv[a + 3]};
        for (int cc = 0; cc < nch; ++cc) {
            f4 v = *(const f4*)(facc_part + (slot0 + cc) * 8192 + (rbase + row) * 64 + a);
            acc += v;
        }
        acc *= linv[row];
        *(f4*)(ob + e) = acc;
    }
}

// ---------------------------------------------------------------------------
extern "C" void kernel_launch(void* const* d_in, const int* in_sizes, int n_in,
                              void* d_out, int out_size, void* d_ws, size_t ws_size,
                              hipStream_t stream) {
    const float* query = (const float*)d_in[0];
    const float* key   = (const float*)d_in[1];
    const float* value = (const float*)d_in[2];
    const float* Wq    = (const float*)d_in[3];
    const float* bq    = (const float*)d_in[4];
    const float* Wk    = (const float*)d_in[5];
    const float* bk    = (const float*)d_in[6];
    const float* Wv    = (const float*)d_in[7];
    const float* bv    = (const float*)d_in[8];

    char* ws = (char*)d_ws;
    const size_t MB = 1u << 20;
    unsigned short* q_hi = (unsigned short*)(ws + 0 * MB);    // 2 MB
    unsigned short* q_lo = (unsigned short*)(ws + 2 * MB);    // 2 MB
    unsigned short* kv   = (unsigned short*)(ws + 4 * MB);    // 6.3 MB
    float* sufv      = (float*)(ws + 12 * MB);                // 64 KB
    float* l_part    = (float*)(ws + 13 * MB);                // 557 KB
    float* facc_part = (float*)(ws + 14 * MB);                // 35.7 MB
    unsigned short* wt_h = (unsigned short*)(ws + 52 * MB);   // 192 KB
    unsigned short* wt_l = wt_h + 3 * AA * EE;                // 192 KB

    split_w_kernel<<<(3 * EE * AA + 255) / 256, 256, 0, stream>>>(Wq, Wk, Wv, wt_h, wt_l);
    proj_kernel<<<dim3(BB * SS / 32, 3), 128, 0, stream>>>(
        query, key, value, bq, bk, bv, wt_h, wt_l, q_hi, q_lo, kv);
    sufv_kernel<<<BB * AA, 64, 0, stream>>>(kv, sufv);
    attn_chunk_kernel<<<dim3(4 * NSLOT, 1), 512, 0, stream>>>(
        q_hi, q_lo, kv, facc_part, l_part);
    combine_kernel<<<dim3(NT, BB), 256, 0, stream>>>(facc_part, l_part, sufv, (float*)d_out);
}